// Round 2
// baseline (24.523 us; speedup 1.0000x reference)
//
#include <hip/hip_runtime.h>

// Problem constants (from reference)
#define PAD_LEN 64
#define DD      128
#define N_ITEMS 4096   // BSZ * N = 64 * 64

// Layout: 256-thread block = 4 waves = 2 items.
//   waves (0,1) -> item 2b+0 ; waves (2,3) -> item 2b+1
//   each wave handles 32 of the 64 tokens (half_item = wave&1)
// Within a wave: half-wave h (lane>>5) processes token 2j+h each iter,
//   lane (l&31) holds float4 = columns [4*(l&31) .. +3] (32 lanes x 16B = full row).
// => each global_load_dwordx4 wave-instruction fetches TWO token rows (1 KB).
__global__ __launch_bounds__(256, 8) void avg_encoder_kernel(
    const int*   __restrict__ ids,       // [N_ITEMS]
    const int*   __restrict__ tokens,    // [N_I, PAD_LEN]
    const float* __restrict__ lens,      // [N_I]
    const float* __restrict__ emb,       // [VOCAB, DD]
    float*       __restrict__ out)       // [N_ITEMS, DD]
{
    __shared__ float lds_part[2][DD];

    const int tid         = threadIdx.x;
    const int lane        = tid & 63;
    const int wave        = tid >> 6;      // 0..3
    const int item_in_blk = wave >> 1;     // 0..1
    const int half_item   = wave & 1;      // which 32-token half this wave owns
    const int sub         = lane & 31;     // column group 0..31
    const int h           = lane >> 5;     // half-wave 0/1
    const int item        = blockIdx.x * 2 + item_in_blk;

    const int  id   = ids[item];                              // wave-uniform
    const int* trow = tokens + id * PAD_LEN + half_item * 32; // this wave's 32 tokens

    float4 acc = make_float4(0.f, 0.f, 0.f, 0.f);

    #pragma unroll 8
    for (int j = 0; j < 16; ++j) {
        const int t = trow[2 * j + h];                        // uniform per half-wave, L1-hit
        const float4 e = *reinterpret_cast<const float4*>(
            emb + (unsigned)t * (unsigned)DD + (unsigned)(sub * 4));
        acc.x += e.x; acc.y += e.y; acc.z += e.z; acc.w += e.w;
    }

    // combine the two half-waves (both halves end with the full 32-token sum)
    acc.x += __shfl(acc.x, lane ^ 32, 64);
    acc.y += __shfl(acc.y, lane ^ 32, 64);
    acc.z += __shfl(acc.z, lane ^ 32, 64);
    acc.w += __shfl(acc.w, lane ^ 32, 64);

    // cross-wave combine via LDS: odd wave publishes, even wave reduces+writes
    if (half_item == 1 && h == 0)
        *reinterpret_cast<float4*>(&lds_part[item_in_blk][sub * 4]) = acc;

    __syncthreads();

    if (half_item == 0 && h == 0) {
        const float4 o =
            *reinterpret_cast<const float4*>(&lds_part[item_in_blk][sub * 4]);
        const float inv_len = 1.0f / lens[id];
        float4 r;
        r.x = (acc.x + o.x) * inv_len;
        r.y = (acc.y + o.y) * inv_len;
        r.z = (acc.z + o.z) * inv_len;
        r.w = (acc.w + o.w) * inv_len;
        *reinterpret_cast<float4*>(out + (size_t)item * DD + (size_t)(sub * 4)) = r;
    }
}

extern "C" void kernel_launch(void* const* d_in, const int* in_sizes, int n_in,
                              void* d_out, int out_size, void* d_ws, size_t ws_size,
                              hipStream_t stream) {
    const int*   ids    = (const int*)  d_in[0];
    const int*   tokens = (const int*)  d_in[1];
    const float* lens   = (const float*)d_in[2];
    const float* emb    = (const float*)d_in[3];
    float*       out    = (float*)d_out;

    const int grid = N_ITEMS / 2;   // 2048 blocks of 256 threads (2 items/block)
    avg_encoder_kernel<<<grid, 256, 0, stream>>>(ids, tokens, lens, emb, out);
}

// Round 3
// 22.794 us; speedup vs baseline: 1.0759x; 1.0759x over previous
//
#include <hip/hip_runtime.h>
#include <stdint.h>

// Problem constants (from reference)
#define PAD_LEN 64
#define DD      128
#define N_ITEMS 4096    // BSZ * N
#define VOCAB   50000

// ---------------------------------------------------------------------------
// Pre-pass: convert f32 embedding table -> bf16 (round-to-nearest-even) in ws.
// 6.4M floats; each thread converts one float4 -> ushort4 (coalesced).
// ---------------------------------------------------------------------------
__global__ __launch_bounds__(256) void cvt_bf16_kernel(
    const float4*  __restrict__ src,   // VOCAB*DD/4 float4
    ushort4*       __restrict__ dst,
    int n4)
{
    const int i = blockIdx.x * 256 + threadIdx.x;
    if (i >= n4) return;
    const float4 v = src[i];
    ushort4 o;
    uint32_t u;
    u = __float_as_uint(v.x); u += 0x7FFFu + ((u >> 16) & 1u); o.x = (unsigned short)(u >> 16);
    u = __float_as_uint(v.y); u += 0x7FFFu + ((u >> 16) & 1u); o.y = (unsigned short)(u >> 16);
    u = __float_as_uint(v.z); u += 0x7FFFu + ((u >> 16) & 1u); o.z = (unsigned short)(u >> 16);
    u = __float_as_uint(v.w); u += 0x7FFFu + ((u >> 16) & 1u); o.w = (unsigned short)(u >> 16);
    dst[i] = o;
}

// ---------------------------------------------------------------------------
// Main gather: one wave per item. bf16 row = 256 B = 32 ushort4.
// Half-wave h (lane>>5) processes token 2j+h; lane sub (lane&31) holds
// columns [4sub..4sub+3]. One wave-instruction fetches TWO bf16 rows (512 B).
// f32 accumulation; halves combined via shfl-xor-32.
// ---------------------------------------------------------------------------
__global__ __launch_bounds__(256) void avg_gather_bf16_kernel(
    const int*     __restrict__ ids,      // [N_ITEMS]
    const int*     __restrict__ tokens,   // [N_I, PAD_LEN]
    const float*   __restrict__ lens,     // [N_I]
    const ushort4* __restrict__ emb16,    // [VOCAB, 32] (bf16 rows)
    float*         __restrict__ out)      // [N_ITEMS, DD]
{
    const int lane = threadIdx.x & 63;
    const int wave = threadIdx.x >> 6;        // 0..3
    const int item = blockIdx.x * 4 + wave;
    const int sub  = lane & 31;
    const int h    = lane >> 5;

    const int  id   = ids[item];              // wave-uniform
    const int* trow = tokens + id * PAD_LEN;

    float ax = 0.f, ay = 0.f, az = 0.f, aw = 0.f;

    #pragma unroll 16
    for (int j = 0; j < 32; ++j) {
        const int t = trow[2 * j + h];        // uniform per half-wave (L1 broadcast)
        const ushort4 e = emb16[(unsigned)t * 32u + (unsigned)sub];
        ax += __uint_as_float((uint32_t)e.x << 16);
        ay += __uint_as_float((uint32_t)e.y << 16);
        az += __uint_as_float((uint32_t)e.z << 16);
        aw += __uint_as_float((uint32_t)e.w << 16);
    }

    // combine the two half-waves (each summed 32 tokens)
    ax += __shfl(ax, lane ^ 32, 64);
    ay += __shfl(ay, lane ^ 32, 64);
    az += __shfl(az, lane ^ 32, 64);
    aw += __shfl(aw, lane ^ 32, 64);

    if (h == 0) {
        const float inv_len = 1.0f / lens[id];
        float4 r;
        r.x = ax * inv_len; r.y = ay * inv_len;
        r.z = az * inv_len; r.w = aw * inv_len;
        *reinterpret_cast<float4*>(out + (size_t)item * DD + (size_t)(sub * 4)) = r;
    }
}

// ---------------------------------------------------------------------------
// Fallback (ws too small): R1 f32 kernel — one wave per item, float2 lanes.
// ---------------------------------------------------------------------------
__global__ __launch_bounds__(256) void avg_gather_f32_kernel(
    const int*   __restrict__ ids,
    const int*   __restrict__ tokens,
    const float* __restrict__ lens,
    const float* __restrict__ emb,
    float*       __restrict__ out)
{
    const int lane = threadIdx.x & 63;
    const int wave = threadIdx.x >> 6;
    const int item = blockIdx.x * 4 + wave;

    const int   id      = ids[item];
    const float inv_len = 1.0f / lens[id];
    const int*  trow    = tokens + id * PAD_LEN;

    float accx = 0.0f, accy = 0.0f;
    #pragma unroll 8
    for (int k = 0; k < PAD_LEN; ++k) {
        const int tok = trow[k];
        const float2 e =
            *reinterpret_cast<const float2*>(emb + (size_t)tok * DD + lane * 2);
        accx += e.x;
        accy += e.y;
    }
    float2 r;
    r.x = accx * inv_len;
    r.y = accy * inv_len;
    *reinterpret_cast<float2*>(out + (size_t)item * DD + lane * 2) = r;
}

extern "C" void kernel_launch(void* const* d_in, const int* in_sizes, int n_in,
                              void* d_out, int out_size, void* d_ws, size_t ws_size,
                              hipStream_t stream) {
    const int*   ids    = (const int*)  d_in[0];
    const int*   tokens = (const int*)  d_in[1];
    const float* lens   = (const float*)d_in[2];
    const float* emb    = (const float*)d_in[3];
    float*       out    = (float*)d_out;

    const size_t need = (size_t)VOCAB * DD * sizeof(unsigned short);  // 12.8 MB

    if (ws_size >= need) {
        ushort4* emb16 = (ushort4*)d_ws;
        const int n4 = VOCAB * DD / 4;                 // 1.6M float4s
        cvt_bf16_kernel<<<(n4 + 255) / 256, 256, 0, stream>>>(
            (const float4*)emb, emb16, n4);
        avg_gather_bf16_kernel<<<N_ITEMS / 4, 256, 0, stream>>>(
            ids, tokens, lens, emb16, out);
    } else {
        avg_gather_f32_kernel<<<N_ITEMS / 4, 256, 0, stream>>>(
            ids, tokens, lens, emb, out);
    }
}